// Round 1
// baseline (1016.716 us; speedup 1.0000x reference)
//
#include <hip/hip_runtime.h>
#include <math.h>

// DownConvFace: 3 stages of {mesh_conv -> BN(global stats) -> (+res) -> LeakyReLU(0.2)}
// B=4, F=50000, Cin=32 (stage1) / 64 (stages 2,3), O=64. All fp32, NCHW-ish [B][C][F].
//
// Per stage: conv -> stats(partial sums, deterministic 2-level) -> finalize(mu,rsig ->
// fused scale/shift) -> norm(+residual, leaky relu, in-place safe).
// Buffers: d_out and d_ws each hold one [B][64][F] fp32 tensor (51.2 MB); partials+mr
// live right after bufA in d_ws.

#define NB_STATS 16

template <int CIN>
__launch_bounds__(256, 2)
__global__ void conv_kernel(const float* __restrict__ x,    // [B][CIN][F]
                            const int*   __restrict__ gidx, // [B][F][3]
                            const float* __restrict__ w,    // [64][CIN][4]
                            const float* __restrict__ bias, // [64]
                            float*       __restrict__ y,    // [B][64][F]
                            int F)
{
    const int b = blockIdx.y;
    const int f = blockIdx.x * blockDim.x + threadIdx.x;
    if (f >= F) return;

    const float* xb = x + (size_t)b * CIN * F;
    const int*   gp = gidx + ((size_t)b * F + f) * 3;
    const int g0 = gp[0], g1 = gp[1], g2 = gp[2];

    float acc[64];
#pragma unroll
    for (int o = 0; o < 64; ++o) acc[o] = bias[o];

    const float4* w4 = (const float4*)w;  // w4[o*CIN + c] = {w[o][c][0..3]}

    for (int c = 0; c < CIN; ++c) {
        const float* row = xb + (size_t)c * F;
        const float ctr = row[f];
        const float a  = row[g0];
        const float bb = row[g1];
        const float cc = row[g2];
        const float s  = a + bb + cc;
        const float dd = fabsf(a - bb) + fabsf(bb - cc) + fabsf(cc - a);
        const float mm = fmaxf(a, fmaxf(bb, cc));
#pragma unroll
        for (int o = 0; o < 64; ++o) {
            const float4 wv = w4[o * CIN + c];  // wave-uniform -> scalar loads
            float t = acc[o];
            t = fmaf(wv.x, ctr, t);
            t = fmaf(wv.y, s,   t);
            t = fmaf(wv.z, dd,  t);
            t = fmaf(wv.w, mm,  t);
            acc[o] = t;
        }
    }

    float* yb = y + (size_t)b * 64 * F + f;
#pragma unroll
    for (int o = 0; o < 64; ++o) yb[(size_t)o * F] = acc[o];
}

// grid: (NB_STATS, 64). partial layout: [2][NB_STATS][64] (sum, then sumsq)
__global__ void stats_kernel(const float* __restrict__ y, float* __restrict__ partial, int F)
{
    const int o = blockIdx.y;
    const int j = blockIdx.x;
    const int stride = NB_STATS * blockDim.x;

    float s = 0.f, sq = 0.f;
    for (int b = 0; b < 4; ++b) {
        const float* row = y + ((size_t)b * 64 + o) * F;
        for (int f = j * blockDim.x + threadIdx.x; f < F; f += stride) {
            const float v = row[f];
            s += v;
            sq += v * v;
        }
    }
    // wave reduce (wave64)
#pragma unroll
    for (int off = 32; off > 0; off >>= 1) {
        s  += __shfl_down(s,  off);
        sq += __shfl_down(sq, off);
    }
    __shared__ float red[2][8];
    const int lane = threadIdx.x & 63;
    const int wid  = threadIdx.x >> 6;
    if (lane == 0) { red[0][wid] = s; red[1][wid] = sq; }
    __syncthreads();
    if (threadIdx.x == 0) {
        float S = 0.f, SQ = 0.f;
        const int nw = blockDim.x >> 6;
        for (int wv = 0; wv < nw; ++wv) { S += red[0][wv]; SQ += red[1][wv]; }
        partial[j * 64 + o] = S;
        partial[NB_STATS * 64 + j * 64 + o] = SQ;
    }
}

// 1 block, 64 threads. mr[o] = gamma*rsig (scale); mr[64+o] = beta - scale*mu (shift)
__global__ void finalize_kernel(const float* __restrict__ partial, float invN,
                                const float* __restrict__ gamma,
                                const float* __restrict__ beta,
                                float* __restrict__ mr)
{
    const int o = threadIdx.x;
    float S = 0.f, SQ = 0.f;
    for (int j = 0; j < NB_STATS; ++j) {
        S  += partial[j * 64 + o];
        SQ += partial[NB_STATS * 64 + j * 64 + o];
    }
    const float mu  = S * invN;
    const float var = SQ * invN - mu * mu;
    const float rs  = rsqrtf(var + 1e-5f);
    const float sc  = gamma[o] * rs;
    mr[o]      = sc;
    mr[64 + o] = fmaf(-sc, mu, beta[o]);
}

// grid: (ceil(F/256), B*64). In-place safe (same-index elementwise).
__global__ void norm_kernel(const float* __restrict__ y,
                            const float* __restrict__ res,  // may be null
                            const float* __restrict__ mr,
                            float* __restrict__ out, int F)
{
    const int bo = blockIdx.y;
    const int o  = bo & 63;
    const int f  = blockIdx.x * blockDim.x + threadIdx.x;
    if (f >= F) return;
    const size_t i = (size_t)bo * F + f;
    float v = fmaf(y[i], mr[o], mr[64 + o]);
    if (res) v += res[i];
    out[i] = (v >= 0.f) ? v : 0.2f * v;
}

extern "C" void kernel_launch(void* const* d_in, const int* in_sizes, int n_in,
                              void* d_out, int out_size, void* d_ws, size_t ws_size,
                              hipStream_t stream)
{
    const float* fe  = (const float*)d_in[0];
    const int*   gm  = (const int*)d_in[1];
    const float* w1  = (const float*)d_in[2];
    const float* b1  = (const float*)d_in[3];
    const float* w2a = (const float*)d_in[4];
    const float* b2a = (const float*)d_in[5];
    const float* w2b = (const float*)d_in[6];
    const float* b2b = (const float*)d_in[7];
    const float* g0  = (const float*)d_in[8];
    const float* be0 = (const float*)d_in[9];
    const float* g1  = (const float*)d_in[10];
    const float* be1 = (const float*)d_in[11];
    const float* g2  = (const float*)d_in[12];
    const float* be2 = (const float*)d_in[13];

    const int B = 4, CIN = 32, O = 64;
    const int F = in_sizes[0] / (B * CIN);
    const float invN = 1.0f / (float)(B * F);

    float* out     = (float*)d_out;                    // [B][64][F]
    float* bufA    = (float*)d_ws;                     // [B][64][F]
    float* partial = bufA + (size_t)B * O * F;         // [2][NB_STATS][64]
    float* mr      = partial + 2 * NB_STATS * 64;      // [2][64]

    dim3 blk(256);
    dim3 cgrid((F + 255) / 256, B);
    dim3 sgrid(NB_STATS, 64);
    dim3 ngrid((F + 255) / 256, B * O);

    // ---- Stage 1: conv1(fe) -> out; BN+lrelu in-place on out => x1 ----
    conv_kernel<32><<<cgrid, blk, 0, stream>>>(fe, gm, w1, b1, out, F);
    stats_kernel<<<sgrid, blk, 0, stream>>>(out, partial, F);
    finalize_kernel<<<1, 64, 0, stream>>>(partial, invN, g0, be0, mr);
    norm_kernel<<<ngrid, blk, 0, stream>>>(out, nullptr, mr, out, F);

    // ---- Stage 2: conv2a(x1=out) -> bufA; BN + res(x1) + lrelu in-place => x2 ----
    conv_kernel<64><<<cgrid, blk, 0, stream>>>(out, gm, w2a, b2a, bufA, F);
    stats_kernel<<<sgrid, blk, 0, stream>>>(bufA, partial, F);
    finalize_kernel<<<1, 64, 0, stream>>>(partial, invN, g1, be1, mr);
    norm_kernel<<<ngrid, blk, 0, stream>>>(bufA, out, mr, bufA, F);

    // ---- Stage 3: conv2b(x2=bufA) -> out; BN + res(x2) + lrelu in-place => result ----
    conv_kernel<64><<<cgrid, blk, 0, stream>>>(bufA, gm, w2b, b2b, out, F);
    stats_kernel<<<sgrid, blk, 0, stream>>>(out, partial, F);
    finalize_kernel<<<1, 64, 0, stream>>>(partial, invN, g2, be2, mr);
    norm_kernel<<<ngrid, blk, 0, stream>>>(out, bufA, mr, out, F);
}

// Round 2
// 869.899 us; speedup vs baseline: 1.1688x; 1.1688x over previous
//
#include <hip/hip_runtime.h>
#include <math.h>

// DownConvFace: 3 stages of {mesh_conv -> BN(global stats) -> (+res) -> LeakyReLU(0.2)}
// B=4, F=50000, Cin=32/64/64, O=64, fp32 in/out.
//
// R1 change: conv is now a fused gather->LDS->MFMA GEMM:
//   Y[b,o,f] = sum_ck W_bf16[o,ck] * G_bf16[ck, f] + bias[o],  K = 4*CIN, ck = 4c+kk
// G built in LDS per 64-face tile (bf16), W pre-cast to bf16 (flat cast, layout
// [O][C][4] == [O][K]). MFMA 16x16x32_bf16, fp32 accumulate.
// Verified layouts (per guide §3): A[m=lane&15][k=(lane>>4)*8+j],
// B[n=lane&15][k=(lane>>4)*8+j], C/D[col=lane&15][row=(lane>>4)*4+reg].

#define NB_STATS 16

typedef __attribute__((ext_vector_type(8))) short short8;
typedef __attribute__((ext_vector_type(4))) float f32x4;

__device__ inline unsigned short f2bf(float v) {
    union { float f; unsigned u; } x; x.f = v;
    unsigned r = x.u + 0x7fffu + ((x.u >> 16) & 1u);   // RNE
    return (unsigned short)(r >> 16);
}

// Cast all three weight tensors fp32->bf16 (flat; [O][C][4] == [O][4C] with ck=4c+kk).
__global__ void cast_weights_kernel(const float* __restrict__ w1,
                                    const float* __restrict__ w2a,
                                    const float* __restrict__ w2b,
                                    unsigned short* __restrict__ w1b,
                                    unsigned short* __restrict__ w2ab,
                                    unsigned short* __restrict__ w2bb)
{
    const int i = blockIdx.x * blockDim.x + threadIdx.x;
    if (i < 64 * 128) w1b[i] = f2bf(w1[i]);
    if (i < 64 * 256) { w2ab[i] = f2bf(w2a[i]); w2bb[i] = f2bf(w2b[i]); }
}

// Fused mesh-conv GEMM. Block: 256 thr (4 waves), tile M=64(all o) x N=64 faces.
// grid = (ceil(F/64), B).
template <int CIN>
__launch_bounds__(256, 4)
__global__ void conv_mfma_kernel(const float* __restrict__ x,     // [B][CIN][F]
                                 const int*   __restrict__ gidx,  // [B][F][3]
                                 const unsigned short* __restrict__ wb, // [64][K] bf16
                                 const float* __restrict__ bias,  // [64]
                                 float*       __restrict__ y,     // [B][64][F]
                                 int F)
{
    constexpr int K   = 4 * CIN;
    constexpr int LDK = K + 8;           // +8 bf16 pad: rows 16B-aligned, 2-way-max banks
    __shared__ unsigned short Gs[64 * LDK];

    const int b  = blockIdx.y;
    const int f0 = blockIdx.x * 64;
    const int t  = threadIdx.x;

    // ---- phase 1: gather + feature build into LDS (bf16) ----
    // thread t -> face j = t&63, channel-quarter h = t>>6 (CIN/4 channels each)
    {
        const int j = t & 63;
        const int h = t >> 6;
        const int f = f0 + j;
        unsigned short* gr = &Gs[j * LDK];
        if (f < F) {
            const float* xb = x + (size_t)b * CIN * F;
            const int* gp = gidx + ((size_t)b * F + f) * 3;
            const int g0 = gp[0], g1 = gp[1], g2 = gp[2];
#pragma unroll
            for (int cc = 0; cc < CIN / 4; ++cc) {
                const int c = h * (CIN / 4) + cc;
                const float* row = xb + (size_t)c * F;
                const float ctr = row[f];
                const float a  = row[g0];
                const float bv = row[g1];
                const float cv = row[g2];
                const float s  = a + bv + cv;
                const float dd = fabsf(a - bv) + fabsf(bv - cv) + fabsf(cv - a);
                const float mm = fmaxf(a, fmaxf(bv, cv));
                ushort4 q;
                q.x = f2bf(ctr); q.y = f2bf(s); q.z = f2bf(dd); q.w = f2bf(mm);
                *(ushort4*)(gr + 4 * c) = q;
            }
        } else {
            ushort4 z; z.x = z.y = z.z = z.w = 0;
#pragma unroll
            for (int cc = 0; cc < CIN / 4; ++cc) {
                const int c = h * (CIN / 4) + cc;
                *(ushort4*)(gr + 4 * c) = z;
            }
        }
    }
    __syncthreads();

    // ---- phase 2: MFMA. wave w -> n-subtile [w*16, w*16+16), all 4 m-tiles ----
    const int lane = t & 63;
    const int wv   = t >> 6;
    const int l15  = lane & 15;
    const int quad = lane >> 4;
    const int kb   = quad * 8;

    f32x4 acc[4];
#pragma unroll
    for (int mt = 0; mt < 4; ++mt) acc[mt] = (f32x4){0.f, 0.f, 0.f, 0.f};

    const int n = wv * 16 + l15;
#pragma unroll
    for (int ks = 0; ks < K; ks += 32) {
        const short8 bfr = *(const short8*)&Gs[n * LDK + ks + kb];
#pragma unroll
        for (int mt = 0; mt < 4; ++mt) {
            const short8 afr = *(const short8*)(wb + (size_t)(mt * 16 + l15) * K + ks + kb);
            acc[mt] = __builtin_amdgcn_mfma_f32_16x16x32_bf16(afr, bfr, acc[mt], 0, 0, 0);
        }
    }

    // ---- epilogue: D[col=l15][row=quad*4+r] -> y[b][o][f] + bias ----
    const int fcol = f0 + wv * 16 + l15;
    if (fcol < F) {
        float* yb = y + (size_t)b * 64 * F + fcol;
#pragma unroll
        for (int mt = 0; mt < 4; ++mt) {
#pragma unroll
            for (int r = 0; r < 4; ++r) {
                const int o = mt * 16 + quad * 4 + r;
                yb[(size_t)o * F] = acc[mt][r] + bias[o];
            }
        }
    }
}

// grid: (NB_STATS, 64). partial layout: [2][NB_STATS][64] (sum, then sumsq)
__global__ void stats_kernel(const float* __restrict__ y, float* __restrict__ partial, int F)
{
    const int o = blockIdx.y;
    const int j = blockIdx.x;
    const int stride = NB_STATS * blockDim.x;

    float s = 0.f, sq = 0.f;
    for (int b = 0; b < 4; ++b) {
        const float* row = y + ((size_t)b * 64 + o) * F;
        for (int f = j * blockDim.x + threadIdx.x; f < F; f += stride) {
            const float v = row[f];
            s += v;
            sq += v * v;
        }
    }
#pragma unroll
    for (int off = 32; off > 0; off >>= 1) {
        s  += __shfl_down(s,  off);
        sq += __shfl_down(sq, off);
    }
    __shared__ float red[2][8];
    const int lane = threadIdx.x & 63;
    const int wid  = threadIdx.x >> 6;
    if (lane == 0) { red[0][wid] = s; red[1][wid] = sq; }
    __syncthreads();
    if (threadIdx.x == 0) {
        float S = 0.f, SQ = 0.f;
        const int nw = blockDim.x >> 6;
        for (int w = 0; w < nw; ++w) { S += red[0][w]; SQ += red[1][w]; }
        partial[j * 64 + o] = S;
        partial[NB_STATS * 64 + j * 64 + o] = SQ;
    }
}

// 1 block, 64 threads. mr[o] = gamma*rsig; mr[64+o] = beta - scale*mu
__global__ void finalize_kernel(const float* __restrict__ partial, float invN,
                                const float* __restrict__ gamma,
                                const float* __restrict__ beta,
                                float* __restrict__ mr)
{
    const int o = threadIdx.x;
    float S = 0.f, SQ = 0.f;
    for (int j = 0; j < NB_STATS; ++j) {
        S  += partial[j * 64 + o];
        SQ += partial[NB_STATS * 64 + j * 64 + o];
    }
    const float mu  = S * invN;
    const float var = SQ * invN - mu * mu;
    const float rs  = rsqrtf(var + 1e-5f);
    const float sc  = gamma[o] * rs;
    mr[o]      = sc;
    mr[64 + o] = fmaf(-sc, mu, beta[o]);
}

// grid: (ceil(F/256), B*64). Same-index elementwise; in-place safe.
__global__ void norm_kernel(const float* __restrict__ y,
                            const float* __restrict__ res,  // may be null
                            const float* __restrict__ mr,
                            float* __restrict__ out, int F)
{
    const int bo = blockIdx.y;
    const int o  = bo & 63;
    const int f  = blockIdx.x * blockDim.x + threadIdx.x;
    if (f >= F) return;
    const size_t i = (size_t)bo * F + f;
    float v = fmaf(y[i], mr[o], mr[64 + o]);
    if (res) v += res[i];
    out[i] = (v >= 0.f) ? v : 0.2f * v;
}

extern "C" void kernel_launch(void* const* d_in, const int* in_sizes, int n_in,
                              void* d_out, int out_size, void* d_ws, size_t ws_size,
                              hipStream_t stream)
{
    const float* fe  = (const float*)d_in[0];
    const int*   gm  = (const int*)d_in[1];
    const float* w1  = (const float*)d_in[2];
    const float* b1  = (const float*)d_in[3];
    const float* w2a = (const float*)d_in[4];
    const float* b2a = (const float*)d_in[5];
    const float* w2b = (const float*)d_in[6];
    const float* b2b = (const float*)d_in[7];
    const float* g0  = (const float*)d_in[8];
    const float* be0 = (const float*)d_in[9];
    const float* g1  = (const float*)d_in[10];
    const float* be1 = (const float*)d_in[11];
    const float* g2  = (const float*)d_in[12];
    const float* be2 = (const float*)d_in[13];

    const int B = 4, CIN = 32, O = 64;
    const int F = in_sizes[0] / (B * CIN);
    const float invN = 1.0f / (float)(B * F);

    float* out     = (float*)d_out;                 // [B][64][F]
    float* bufA    = (float*)d_ws;                  // [B][64][F] conv output Y
    float* partial = bufA + (size_t)B * O * F;      // [2][NB_STATS][64]
    float* mr      = partial + 2 * NB_STATS * 64;   // [2][64]
    unsigned short* w1b  = (unsigned short*)(mr + 128);       // [64][128] bf16
    unsigned short* w2ab = w1b + 64 * 128;                    // [64][256] bf16
    unsigned short* w2bb = w2ab + 64 * 256;                   // [64][256] bf16

    dim3 blk(256);
    dim3 cgrid((F + 63) / 64, B);
    dim3 sgrid(NB_STATS, 64);
    dim3 ngrid((F + 255) / 256, B * O);

    cast_weights_kernel<<<64, 256, 0, stream>>>(w1, w2a, w2b, w1b, w2ab, w2bb);

    // ---- Stage 1: Y=conv1(fe)->bufA; x1 = lrelu(bn(Y)) -> out ----
    conv_mfma_kernel<32><<<cgrid, blk, 0, stream>>>(fe, gm, w1b, b1, bufA, F);
    stats_kernel<<<sgrid, blk, 0, stream>>>(bufA, partial, F);
    finalize_kernel<<<1, 64, 0, stream>>>(partial, invN, g0, be0, mr);
    norm_kernel<<<ngrid, blk, 0, stream>>>(bufA, nullptr, mr, out, F);

    // ---- Stage 2: Y=conv2a(x1)->bufA; x2 = lrelu(bn(Y)+x1) -> out (in-place res) ----
    conv_mfma_kernel<64><<<cgrid, blk, 0, stream>>>(out, gm, w2ab, b2a, bufA, F);
    stats_kernel<<<sgrid, blk, 0, stream>>>(bufA, partial, F);
    finalize_kernel<<<1, 64, 0, stream>>>(partial, invN, g1, be1, mr);
    norm_kernel<<<ngrid, blk, 0, stream>>>(bufA, out, mr, out, F);

    // ---- Stage 3: Y=conv2b(x2)->bufA; x3 = lrelu(bn(Y)+x2) -> out ----
    conv_mfma_kernel<64><<<cgrid, blk, 0, stream>>>(out, gm, w2bb, b2b, bufA, F);
    stats_kernel<<<sgrid, blk, 0, stream>>>(bufA, partial, F);
    finalize_kernel<<<1, 64, 0, stream>>>(partial, invN, g2, be2, mr);
    norm_kernel<<<ngrid, blk, 0, stream>>>(bufA, out, mr, out, F);
}

// Round 3
// 415.833 us; speedup vs baseline: 2.4450x; 2.0919x over previous
//
#include <hip/hip_runtime.h>
#include <math.h>

// DownConvFace: 3 stages of {mesh_conv -> BN(global stats) -> (+res) -> LeakyReLU(0.2)}
// B=4, F=50000, Cin=32/64/64, O=64, fp32 in/out.
//
// R2 change: face-major bf16 activation layout [B][F][C] so each neighbor gather is
// one contiguous 64/128-B read (R1 fetched 732 MB/conv from 4-B scattered gathers in
// [B][C][F] layout). Conv = gather->LDS->MFMA GEMM, Y in [B*F][64] fp32. Stats/norm
// coalesced in face-major; final norm fused with transpose back to [B][64][F].

#define NB_STATS 256

typedef __attribute__((ext_vector_type(8))) short short8;
typedef __attribute__((ext_vector_type(8))) unsigned short ushort8_t;
typedef __attribute__((ext_vector_type(4))) float f32x4;

__device__ inline unsigned short f2bf(float v) {
    union { float f; unsigned u; } x; x.f = v;
    unsigned r = x.u + 0x7fffu + ((x.u >> 16) & 1u);   // RNE
    return (unsigned short)(r >> 16);
}
__device__ inline float bf2f(unsigned short u) {
    union { unsigned u; float f; } x; x.u = ((unsigned)u) << 16; return x.f;
}

// fe [B][32][F] fp32 -> fe_t [B][F][32] bf16. grid (ceil(F/64), B), block 256.
__global__ void transpose_fe_kernel(const float* __restrict__ fe,
                                    unsigned short* __restrict__ o, int F)
{
    __shared__ float tile[64 * 33];
    const int b = blockIdx.y;
    const int f0 = blockIdx.x * 64;
    const int t = threadIdx.x;
    const int lane = t & 63;
    const int w = t >> 6;
    const int f = f0 + lane;
    if (f < F) {
#pragma unroll
        for (int i = 0; i < 8; ++i) {
            const int c = w * 8 + i;
            tile[lane * 33 + c] = fe[((size_t)b * 32 + c) * F + f];
        }
    }
    __syncthreads();
    const int j = t >> 2, s = t & 3;
    const int fj = f0 + j;
    if (fj < F) {
        ushort8_t v;
#pragma unroll
        for (int i = 0; i < 8; ++i) v[i] = f2bf(tile[j * 33 + s * 8 + i]);
        *(ushort8_t*)(o + ((size_t)b * F + fj) * 32 + s * 8) = v;
    }
}

// Cast weights fp32->bf16 (flat; [O][C][4] == [O][4C], k=4c+kk).
__global__ void cast_weights_kernel(const float* __restrict__ w1,
                                    const float* __restrict__ w2a,
                                    const float* __restrict__ w2b,
                                    unsigned short* __restrict__ w1b,
                                    unsigned short* __restrict__ w2ab,
                                    unsigned short* __restrict__ w2bb)
{
    const int i = blockIdx.x * blockDim.x + threadIdx.x;
    if (i < 64 * 128) w1b[i] = f2bf(w1[i]);
    if (i < 64 * 256) { w2ab[i] = f2bf(w2a[i]); w2bb[i] = f2bf(w2b[i]); }
}

// Fused mesh-conv GEMM, face-major bf16 input. Block 256 (4 waves), tile 64 faces x 64 o.
// grid = (ceil(F/64), B). Output Y [B*F][64] fp32.
template <int CIN>
__launch_bounds__(256, 4)
__global__ void conv_mfma_kernel(const unsigned short* __restrict__ x,  // [B][F][CIN] bf16
                                 const int*   __restrict__ gidx,        // [B][F][3]
                                 const unsigned short* __restrict__ wb, // [64][K] bf16
                                 const float* __restrict__ bias,        // [64]
                                 float*       __restrict__ y,           // [B*F][64]
                                 int F)
{
    constexpr int K   = 4 * CIN;
    constexpr int LDK = K + 8;
    __shared__ unsigned short Gs[64 * LDK];

    const int b  = blockIdx.y;
    const int f0 = blockIdx.x * 64;
    const int t  = threadIdx.x;

    // ---- phase 1: gather contiguous bf16 rows, build features into LDS ----
    {
        const int j = t >> 2, s = t & 3;       // 4 threads per face
        const int f = f0 + j;
        unsigned short* gr = &Gs[j * LDK];
        if (f < F) {
            const unsigned short* xb = x + (size_t)b * F * CIN;
            const int* gp = gidx + ((size_t)b * F + f) * 3;
            const int g0 = gp[0], g1 = gp[1], g2 = gp[2];
            const unsigned short* pc = xb + (size_t)f  * CIN;
            const unsigned short* p0 = xb + (size_t)g0 * CIN;
            const unsigned short* p1 = xb + (size_t)g1 * CIN;
            const unsigned short* p2 = xb + (size_t)g2 * CIN;
#pragma unroll
            for (int i = 0; i < CIN / 32; ++i) {
                const int c0 = (i * 4 + s) * 8;     // 8-channel chunk, 16B loads
                const ushort8_t vc = *(const ushort8_t*)(pc + c0);
                const ushort8_t v0 = *(const ushort8_t*)(p0 + c0);
                const ushort8_t v1 = *(const ushort8_t*)(p1 + c0);
                const ushort8_t v2 = *(const ushort8_t*)(p2 + c0);
                unsigned short feat[32];
#pragma unroll
                for (int q = 0; q < 8; ++q) {
                    const float ctr = bf2f(vc[q]);
                    const float a   = bf2f(v0[q]);
                    const float bb  = bf2f(v1[q]);
                    const float cc  = bf2f(v2[q]);
                    const float su  = a + bb + cc;
                    const float dd  = fabsf(a - bb) + fabsf(bb - cc) + fabsf(cc - a);
                    const float mm  = fmaxf(a, fmaxf(bb, cc));
                    feat[4 * q + 0] = f2bf(ctr);
                    feat[4 * q + 1] = f2bf(su);
                    feat[4 * q + 2] = f2bf(dd);
                    feat[4 * q + 3] = f2bf(mm);
                }
#pragma unroll
                for (int q4 = 0; q4 < 4; ++q4)
                    *(ushort8_t*)(gr + 4 * c0 + q4 * 8) = *(ushort8_t*)(feat + q4 * 8);
            }
        } else {
            ushort8_t z = {0, 0, 0, 0, 0, 0, 0, 0};
#pragma unroll
            for (int i = 0; i < CIN / 32; ++i) {
                const int c0 = (i * 4 + s) * 8;
#pragma unroll
                for (int q4 = 0; q4 < 4; ++q4)
                    *(ushort8_t*)(gr + 4 * c0 + q4 * 8) = z;
            }
        }
    }
    __syncthreads();

    // ---- phase 2: MFMA (layouts verified in R1: passed end-to-end) ----
    const int lane = t & 63, wv = t >> 6;
    const int l15 = lane & 15, quad = lane >> 4;
    const int kb = quad * 8;

    f32x4 acc[4];
#pragma unroll
    for (int mt = 0; mt < 4; ++mt) acc[mt] = (f32x4){0.f, 0.f, 0.f, 0.f};

    const int n = wv * 16 + l15;
#pragma unroll
    for (int ks = 0; ks < K; ks += 32) {
        const short8 bfr = *(const short8*)&Gs[n * LDK + ks + kb];
#pragma unroll
        for (int mt = 0; mt < 4; ++mt) {
            const short8 afr = *(const short8*)(wb + (size_t)(mt * 16 + l15) * K + ks + kb);
            acc[mt] = __builtin_amdgcn_mfma_f32_16x16x32_bf16(afr, bfr, acc[mt], 0, 0, 0);
        }
    }

    // ---- epilogue: D[col=l15 -> face][row=quad*4+r -> o] + bias -> Y[b*F+f][o] ----
    const int fcol = f0 + wv * 16 + l15;
    if (fcol < F) {
        float* yb = y + ((size_t)b * F + fcol) * 64;
#pragma unroll
        for (int mt = 0; mt < 4; ++mt) {
            const int ob = mt * 16 + quad * 4;
            const f32x4 b4 = *(const f32x4*)(bias + ob);
            f32x4 r = acc[mt] + b4;
            *(f32x4*)(yb + ob) = r;
        }
    }
}

// Y [M][64] fp32 -> per-channel partial sums. grid NB_STATS, block 256.
__global__ void stats_kernel(const float* __restrict__ y, float* __restrict__ partial, int M)
{
    __shared__ float reds[16 * 64], redq[16 * 64];
    const int t = threadIdx.x, j = blockIdx.x;
    const int g = t >> 4, c0 = (t & 15) * 4;
    f32x4 s = {0.f, 0.f, 0.f, 0.f}, q = {0.f, 0.f, 0.f, 0.f};
    for (int r = j * 16 + g; r < M; r += NB_STATS * 16) {
        const f32x4 v = *(const f32x4*)(y + (size_t)r * 64 + c0);
        s += v;
        q += v * v;
    }
    *(f32x4*)(reds + g * 64 + c0) = s;
    *(f32x4*)(redq + g * 64 + c0) = q;
    __syncthreads();
    if (t < 64) {
        float S = 0.f, Q = 0.f;
#pragma unroll
        for (int gg = 0; gg < 16; ++gg) { S += reds[gg * 64 + t]; Q += redq[gg * 64 + t]; }
        partial[j * 64 + t] = S;
        partial[NB_STATS * 64 + j * 64 + t] = Q;
    }
}

// 1 block, 256 threads. mr[o]=gamma*rsig; mr[64+o]=beta-scale*mu
__global__ void finalize_kernel(const float* __restrict__ partial, float invN,
                                const float* __restrict__ gamma,
                                const float* __restrict__ beta,
                                float* __restrict__ mr)
{
    __shared__ float rs_[4 * 64], rq_[4 * 64];
    const int t = threadIdx.x, o = t & 63, p = t >> 6;
    float S = 0.f, Q = 0.f;
    for (int j = p; j < NB_STATS; j += 4) {
        S += partial[j * 64 + o];
        Q += partial[NB_STATS * 64 + j * 64 + o];
    }
    rs_[p * 64 + o] = S; rq_[p * 64 + o] = Q;
    __syncthreads();
    if (t < 64) {
        S = rs_[t] + rs_[64 + t] + rs_[128 + t] + rs_[192 + t];
        Q = rq_[t] + rq_[64 + t] + rq_[128 + t] + rq_[192 + t];
        const float mu  = S * invN;
        const float var = Q * invN - mu * mu;
        const float rsg = rsqrtf(var + 1e-5f);
        const float sc  = gamma[t] * rsg;
        mr[t]      = sc;
        mr[64 + t] = fmaf(-sc, mu, beta[t]);
    }
}

// BN+res+lrelu, face-major -> bf16 x-buffer. tid covers M*64/4 float4 groups.
__global__ void norm_kernel(const float* __restrict__ y,            // [M][64] fp32
                            const unsigned short* __restrict__ res, // [M][64] bf16 or null
                            const float* __restrict__ mr,
                            unsigned short* __restrict__ out,       // [M][64] bf16
                            int N4)
{
    const int tid = blockIdx.x * blockDim.x + threadIdx.x;
    if (tid >= N4) return;
    const int c0 = (tid & 15) * 4;
    const f32x4 v  = *(const f32x4*)(y + (size_t)tid * 4);
    const f32x4 sc = *(const f32x4*)(mr + c0);
    const f32x4 sh = *(const f32x4*)(mr + 64 + c0);
    float r[4];
#pragma unroll
    for (int q = 0; q < 4; ++q) r[q] = fmaf(v[q], sc[q], sh[q]);
    if (res) {
        const ushort4 u = *(const ushort4*)(res + (size_t)tid * 4);
        r[0] += bf2f(u.x); r[1] += bf2f(u.y); r[2] += bf2f(u.z); r[3] += bf2f(u.w);
    }
    ushort4 o;
    o.x = f2bf(r[0] >= 0.f ? r[0] : 0.2f * r[0]);
    o.y = f2bf(r[1] >= 0.f ? r[1] : 0.2f * r[1]);
    o.z = f2bf(r[2] >= 0.f ? r[2] : 0.2f * r[2]);
    o.w = f2bf(r[3] >= 0.f ? r[3] : 0.2f * r[3]);
    *(ushort4*)(out + (size_t)tid * 4) = o;
}

// Final BN+res+lrelu fused with transpose [B*F][64] -> [B][64][F] fp32 (d_out).
// grid (ceil(F/64), B), block 256. Requires F % 4 == 0 (F=50000 ok).
__global__ void norm_transpose_kernel(const float* __restrict__ y,
                                      const unsigned short* __restrict__ res,
                                      const float* __restrict__ mr,
                                      float* __restrict__ out, int F)
{
    __shared__ float tile[64 * 65];
    const int b = blockIdx.y, f0 = blockIdx.x * 64, t = threadIdx.x;
    const int j = t >> 2, s = t & 3;
    const int f = f0 + j;
    if (f < F) {
        const size_t row = ((size_t)b * F + f) * 64;
#pragma unroll
        for (int i = 0; i < 4; ++i) {
            const int c0 = (i * 4 + s) * 4;
            const f32x4 v  = *(const f32x4*)(y + row + c0);
            const f32x4 sc = *(const f32x4*)(mr + c0);
            const f32x4 sh = *(const f32x4*)(mr + 64 + c0);
            const ushort4 u = *(const ushort4*)(res + row + c0);
            const float rv[4] = {bf2f(u.x), bf2f(u.y), bf2f(u.z), bf2f(u.w)};
#pragma unroll
            for (int q = 0; q < 4; ++q) {
                float vv = fmaf(v[q], sc[q], sh[q]) + rv[q];
                vv = vv >= 0.f ? vv : 0.2f * vv;
                tile[(c0 + q) * 65 + j] = vv;
            }
        }
    }
    __syncthreads();
    const int o = t >> 2;
    float* ob = out + ((size_t)b * 64 + o) * F + f0;
#pragma unroll
    for (int i = 0; i < 4; ++i) {
        const int fs = (i * 4 + s) * 4;
        if (f0 + fs < F) {
            f32x4 v;
#pragma unroll
            for (int q = 0; q < 4; ++q) v[q] = tile[o * 65 + fs + q];
            *(f32x4*)(ob + fs) = v;
        }
    }
}

extern "C" void kernel_launch(void* const* d_in, const int* in_sizes, int n_in,
                              void* d_out, int out_size, void* d_ws, size_t ws_size,
                              hipStream_t stream)
{
    const float* fe  = (const float*)d_in[0];
    const int*   gm  = (const int*)d_in[1];
    const float* w1  = (const float*)d_in[2];
    const float* b1  = (const float*)d_in[3];
    const float* w2a = (const float*)d_in[4];
    const float* b2a = (const float*)d_in[5];
    const float* w2b = (const float*)d_in[6];
    const float* b2b = (const float*)d_in[7];
    const float* g0  = (const float*)d_in[8];
    const float* be0 = (const float*)d_in[9];
    const float* g1  = (const float*)d_in[10];
    const float* be1 = (const float*)d_in[11];
    const float* g2  = (const float*)d_in[12];
    const float* be2 = (const float*)d_in[13];

    const int B = 4, O = 64;
    const int F = in_sizes[0] / (B * 32);
    const int M = B * F;
    const float invN = 1.0f / (float)M;

    // Workspace: bufY fp32 [M][64] (51.2MB) + xbuf bf16 [M][64] (25.6MB) + small.
    float*          bufY    = (float*)d_ws;
    unsigned short* xbuf    = (unsigned short*)(bufY + (size_t)M * O);
    float*          partial = (float*)(xbuf + (size_t)M * O);      // [2][NB_STATS][64]
    float*          mr      = partial + 2 * NB_STATS * 64;         // [2][64]
    unsigned short* w1b     = (unsigned short*)(mr + 128);         // [64][128]
    unsigned short* w2ab    = w1b + 64 * 128;                      // [64][256]
    unsigned short* w2bb    = w2ab + 64 * 256;                     // [64][256]
    unsigned short* fe_t    = (unsigned short*)d_out;              // [B][F][32] bf16, dead after conv1

    dim3 blk(256);
    dim3 cgrid((F + 63) / 64, B);
    const int N4 = M * 16;                 // M*64/4
    dim3 ngrid((N4 + 255) / 256);

    transpose_fe_kernel<<<cgrid, blk, 0, stream>>>(fe, fe_t, F);
    cast_weights_kernel<<<64, 256, 0, stream>>>(w1, w2a, w2b, w1b, w2ab, w2bb);

    // ---- Stage 1: Y=conv1(fe_t)->bufY; x1=lrelu(bn(Y)) -> xbuf ----
    conv_mfma_kernel<32><<<cgrid, blk, 0, stream>>>(fe_t, gm, w1b, b1, bufY, F);
    stats_kernel<<<NB_STATS, blk, 0, stream>>>(bufY, partial, M);
    finalize_kernel<<<1, 256, 0, stream>>>(partial, invN, g0, be0, mr);
    norm_kernel<<<ngrid, blk, 0, stream>>>(bufY, nullptr, mr, xbuf, N4);

    // ---- Stage 2: Y=conv2a(x1)->bufY; x2=lrelu(bn(Y)+x1) -> xbuf (in-place res) ----
    conv_mfma_kernel<64><<<cgrid, blk, 0, stream>>>(xbuf, gm, w2ab, b2a, bufY, F);
    stats_kernel<<<NB_STATS, blk, 0, stream>>>(bufY, partial, M);
    finalize_kernel<<<1, 256, 0, stream>>>(partial, invN, g1, be1, mr);
    norm_kernel<<<ngrid, blk, 0, stream>>>(bufY, xbuf, mr, xbuf, N4);

    // ---- Stage 3: Y=conv2b(x2)->bufY; out=lrelu(bn(Y)+x2) transposed -> d_out ----
    conv_mfma_kernel<64><<<cgrid, blk, 0, stream>>>(xbuf, gm, w2bb, b2b, bufY, F);
    stats_kernel<<<NB_STATS, blk, 0, stream>>>(bufY, partial, M);
    finalize_kernel<<<1, 256, 0, stream>>>(partial, invN, g2, be2, mr);
    norm_transpose_kernel<<<cgrid, blk, 0, stream>>>(bufY, xbuf, mr, (float*)d_out, F);
}